// Round 2
// baseline (99.551 us; speedup 1.0000x reference)
//
#include <hip/hip_runtime.h>

// HebbianNet: 3x (GEMV-ish layer + linearized hebbian shift). ALL FP32.
// conv1(1x1,3->MH) -> conv2(1x1,MH->1) with no nonlinearity is a single
// affine map of (vi, w, vj):
//   shift = r*(a0*vi + a1*W + a2*vj + cc),  a_c = sum_h cw2[h]*cw1[h][c],
//   cc = sum_h cw2[h]*cb1[h] + cb2,         r = RATE/batch_num
// => out[b,o] = vj + r*(a0*Sum_i v^2 + a1*dot[b,o] + (a2*vj + cc)*Sum_i v)
// with dot = v@W^T (pre-bias), vj = relu(dot + bias).

#define RATE_F 0.001f

// One layer. n_in fixed at 1024 (all three layers). Block = 256 threads = 4
// waves; wave w computes output row o = blockIdx.x*4 + w for all 8 batches.
__global__ __launch_bounds__(256) void hebb_layer(
    const float* __restrict__ vin,   // (8, 1024) fp32
    const float* __restrict__ W,     // (n_out, 1024) fp32
    const float* __restrict__ bias,  // (n_out,)
    const float* __restrict__ cw1,   // (8,3)
    const float* __restrict__ cb1,   // (8,)
    const float* __restrict__ cw2,   // (1,8)
    const float* __restrict__ cb2,   // (1,)
    const int*   __restrict__ batch_num,
    float*       __restrict__ vout,  // (8, n_out) fp32
    int n_out)
{
    constexpr int NIN = 1024;
    constexpr int BATCH = 8;
    __shared__ float vsh[BATCH * NIN];   // 32 KB staged activations
    __shared__ float coeff[8];           // a0,a1,a2,cc,rate
    __shared__ float svs[BATCH], s2s[BATCH];

    const int tid = threadIdx.x;

    // ---- stage input into LDS ----
    {
        const float4* p = (const float4*)vin;   // 8192 f32 = 2048 float4
        for (int k = tid; k < 2048; k += 256) {
            *(float4*)&vsh[k * 4] = p[k];
        }
    }

    // ---- coefficients (redundant per block; trivial) ----
    if (tid == 0) {
        float a0 = 0.f, a1 = 0.f, a2 = 0.f, cc = 0.f;
        #pragma unroll
        for (int h = 0; h < 8; h++) {
            float w2 = cw2[h];
            a0 += w2 * cw1[h * 3 + 0];
            a1 += w2 * cw1[h * 3 + 1];
            a2 += w2 * cw1[h * 3 + 2];
            cc += w2 * cb1[h];
        }
        cc += cb2[0];
        coeff[0] = a0; coeff[1] = a1; coeff[2] = a2; coeff[3] = cc;
        coeff[4] = RATE_F / (float)batch_num[0];
    }
    __syncthreads();

    // ---- per-batch sum(v) and sum(v^2), from LDS ----
    {
        int b = tid >> 5, j = tid & 31;        // 32 threads per batch row
        float sv = 0.f, s2 = 0.f;
        for (int i = j; i < NIN; i += 32) {
            float v = vsh[b * NIN + i];
            sv += v; s2 += v * v;
        }
        #pragma unroll
        for (int m = 16; m >= 1; m >>= 1) {    // stays within 32-lane halves
            sv += __shfl_xor(sv, m, 64);
            s2 += __shfl_xor(s2, m, 64);
        }
        if (j == 0) { svs[b] = sv; s2s[b] = s2; }
    }
    __syncthreads();

    // ---- dot products: wave per output row ----
    const int w = tid >> 6, lane = tid & 63;
    const int o = blockIdx.x * 4 + w;
    if (o >= n_out) return;

    float acc[BATCH] = {0.f, 0.f, 0.f, 0.f, 0.f, 0.f, 0.f, 0.f};
    const float4* Wrow = (const float4*)(W + (size_t)o * NIN);  // 256 float4
    #pragma unroll
    for (int c = 0; c < 2; c++) {
        const int i0 = c * 512 + lane * 8;     // 8 floats per lane per chunk
        const float4 w0 = Wrow[(i0 >> 2) + 0];
        const float4 w1 = Wrow[(i0 >> 2) + 1];
        #pragma unroll
        for (int b = 0; b < BATCH; b++) {
            const float4 v0 = *(const float4*)&vsh[b * NIN + i0];
            const float4 v1 = *(const float4*)&vsh[b * NIN + i0 + 4];
            acc[b] += w0.x * v0.x + w0.y * v0.y + w0.z * v0.z + w0.w * v0.w
                    + w1.x * v1.x + w1.y * v1.y + w1.z * v1.z + w1.w * v1.w;
        }
    }
    #pragma unroll
    for (int b = 0; b < BATCH; b++) {
        #pragma unroll
        for (int m = 32; m >= 1; m >>= 1)
            acc[b] += __shfl_xor(acc[b], m, 64);
    }

    if (lane < BATCH) {
        const int b = lane;
        const float dot = acc[b];
        float vj = dot + bias[o];
        vj = vj > 0.f ? vj : 0.f;
        const float r = coeff[4];
        const float outv = vj + r * (coeff[0] * s2s[b] + coeff[1] * dot
                                     + (coeff[2] * vj + coeff[3]) * svs[b]);
        vout[(size_t)b * n_out + o] = outv;
    }
}

extern "C" void kernel_launch(void* const* d_in, const int* in_sizes, int n_in,
                              void* d_out, int out_size, void* d_ws, size_t ws_size,
                              hipStream_t stream) {
    const float* x   = (const float*)d_in[0];
    const float* W1  = (const float*)d_in[1];
    const float* b1  = (const float*)d_in[2];
    const float* W2  = (const float*)d_in[3];
    const float* b2  = (const float*)d_in[4];
    const float* W3  = (const float*)d_in[5];
    const float* b3  = (const float*)d_in[6];
    const float* cw1 = (const float*)d_in[7];
    const float* cb1 = (const float*)d_in[8];
    const float* cw2 = (const float*)d_in[9];
    const float* cb2 = (const float*)d_in[10];
    const int*   bn  = (const int*)d_in[11];

    float* v1 = (float*)d_ws;         // 8x1024 fp32 intermediate
    float* v2 = v1 + 8 * 1024;        // 8x1024 fp32 intermediate

    hebb_layer<<<256, 256, 0, stream>>>(x,  W1, b1, cw1, cb1, cw2, cb2, bn, v1, 1024);
    hebb_layer<<<256, 256, 0, stream>>>(v1, W2, b2, cw1, cb1, cw2, cb2, bn, v2, 1024);
    hebb_layer<<<128, 256, 0, stream>>>(v2, W3, b3, cw1, cb1, cw2, cb2, bn, (float*)d_out, 512);
}